// Round 1
// baseline (860.177 us; speedup 1.0000x reference)
//
#include <hip/hip_runtime.h>
#include <hip/hip_bf16.h>

typedef unsigned short u16;
typedef unsigned int   u32;
typedef __attribute__((ext_vector_type(4))) float f4v;
typedef __attribute__((ext_vector_type(8))) short s8v;

#define NB   32      // batch
#define NS   256     // src len
#define NT   8       // dec len
#define NH   512     // hidden
#define NENC 512
#define NEMB 256
#define NVOC 50000
#define NVT  51000

__device__ __forceinline__ float bf2f(u16 u){ return __uint_as_float(((u32)u)<<16); }
__device__ __forceinline__ u16 f2bf(float f){
  u32 x = __float_as_uint(f);
  return (u16)((x + 0x7fffu + ((x>>16)&1u)) >> 16);   // RNE
}
__device__ __forceinline__ s8v ld_frag(const u16* p){
  union{ s8v v; uint2 u[2]; } t;
  t.u[0] = *(const uint2*)p;
  t.u[1] = *(const uint2*)(p+4);
  return t.v;
}
__device__ __forceinline__ f4v mfma16(s8v a, s8v b, f4v c){
  return __builtin_amdgcn_mfma_f32_16x16x32_bf16(a,b,c,0,0,0);
}
__device__ __forceinline__ float sigm(float x){ return 1.f/(1.f+__expf(-x)); }

// ---------------------------------------------------------------------------
// Generic tiled bf16-MFMA GEMM: C[M,N] = epi(A[M,K] @ B[K,N])
//   A: fp32 (converted inline, optional row-gather) or bf16 direct
//   B: fp32 [K][N], transposed-staged to LDS as [n][k] bf16
//   EPI 0: fp32 store   1: bf16 store of tanh(x+bias[n])
//   EPI 2: fp32 store of exp(x) for n<nlim + atomic per-row sums
// Block 256 threads = 4 waves (2x2), wave tile (BM/2)x(BN/2), 16x16x32 MFMA.
// LDS rows stride 36 shorts (72B): 8B-aligned b64 frag reads, conflict-benign.
// ---------------------------------------------------------------------------
template<int BM, int BN, int EPI, bool ABF16, bool AGATHER>
__global__ __launch_bounds__(256)
void gemm_mfma(const void* __restrict__ Av, const float* __restrict__ B,
               float* __restrict__ C, const int* __restrict__ a_idx,
               const float* __restrict__ bias, float* __restrict__ rowsum,
               int K, int lda, int ldb, int ldc, int nlim)
{
  constexpr int LDT = 36;
  __shared__ u16 Al[BM*LDT];
  __shared__ u16 Bl[BN*LDT];
  const int tid  = threadIdx.x;
  const int lane = tid & 63;
  const int wave = tid >> 6;
  const int m0 = blockIdx.x * BM;
  const int n0 = blockIdx.y * BN;
  constexpr int TM = BM/32;
  constexpr int TN = BN/32;
  const int wm = (wave>>1)*(BM/2);
  const int wn = (wave&1)*(BN/2);
  const int q  = lane >> 4;
  const int ln = lane & 15;

  f4v acc[TM][TN];
  #pragma unroll
  for (int im=0; im<TM; ++im)
    #pragma unroll
    for (int in=0; in<TN; ++in) acc[im][in] = 0.f;

  const int KB = K >> 5;
  for (int kb=0; kb<KB; ++kb){
    __syncthreads();
    // ---- stage A tile [BM x 32] -> Al
    if (ABF16){
      const u16* Ag = (const u16*)Av;
      #pragma unroll
      for (int i=0; i<BM/64; ++i){
        int el = tid + i*256;
        int row = el>>2, ck = el&3;
        const u16* src = Ag + (size_t)(m0+row)*lda + kb*32 + ck*8;
        uint2 v0 = *(const uint2*)src;
        uint2 v1 = *(const uint2*)(src+4);
        u16* dst = &Al[row*LDT + ck*8];
        *(uint2*)dst = v0; *(uint2*)(dst+4) = v1;
      }
    } else {
      const float* Ag = (const float*)Av;
      #pragma unroll
      for (int i=0; i<BM/32; ++i){
        int el = tid + i*256;
        int row = el>>3, ck = el&7;
        int grow = AGATHER ? a_idx[m0+row] : (m0+row);
        f4v v = *(const f4v*)(Ag + (size_t)grow*lda + kb*32 + ck*4);
        uint2 p;
        p.x = (u32)f2bf(v.x) | ((u32)f2bf(v.y)<<16);
        p.y = (u32)f2bf(v.z) | ((u32)f2bf(v.w)<<16);
        *(uint2*)&Al[row*LDT + ck*4] = p;
      }
    }
    // ---- stage B tile [32 x BN] transposed -> Bl[n][k]
    {
      constexpr int KP = 256/BN;
      const int nl = tid & (BN-1);
      const int kk = tid / BN;
      #pragma unroll
      for (int i=0; i<32/KP; ++i){
        int k = kk + i*KP;
        int n = n0 + nl;
        int nn = (n < nlim) ? n : (nlim-1);
        Bl[nl*LDT + k] = f2bf(B[(size_t)(kb*32+k)*ldb + nn]);
      }
    }
    __syncthreads();
    // ---- fragments + MFMA
    s8v af[TM], bfr[TN];
    #pragma unroll
    for (int im=0; im<TM; ++im)
      af[im] = ld_frag(&Al[(wm+im*16+ln)*LDT + q*8]);
    #pragma unroll
    for (int in=0; in<TN; ++in)
      bfr[in] = ld_frag(&Bl[(wn+in*16+ln)*LDT + q*8]);
    #pragma unroll
    for (int im=0; im<TM; ++im)
      #pragma unroll
      for (int in=0; in<TN; ++in)
        acc[im][in] = mfma16(af[im], bfr[in], acc[im][in]);
  }

  // ---- epilogue. C/D layout: col = lane&15, row = (lane>>4)*4 + reg
  #pragma unroll
  for (int im=0; im<TM; ++im){
    const int rbase = m0 + wm + im*16 + q*4;
    float rs[4] = {0.f,0.f,0.f,0.f};
    #pragma unroll
    for (int in=0; in<TN; ++in){
      const int col = n0 + wn + in*16 + ln;
      if (EPI == 0){
        #pragma unroll
        for (int r=0; r<4; ++r)
          C[(size_t)(rbase+r)*ldc + col] = acc[im][in][r];
      } else if (EPI == 1){
        float bb = bias[col];
        u16* Cb = (u16*)C;
        #pragma unroll
        for (int r=0; r<4; ++r)
          Cb[(size_t)(rbase+r)*ldc + col] = f2bf(tanhf(acc[im][in][r] + bb));
      } else {
        bool ok = col < nlim;
        #pragma unroll
        for (int r=0; r<4; ++r){
          float e = ok ? __expf(acc[im][in][r]) : 0.f;
          rs[r] += e;
          if (ok) C[(size_t)(rbase+r)*ldc + col] = e;
        }
      }
    }
    if (EPI == 2){
      #pragma unroll
      for (int off=1; off<16; off<<=1){
        rs[0] += __shfl_xor(rs[0], off, 64);
        rs[1] += __shfl_xor(rs[1], off, 64);
        rs[2] += __shfl_xor(rs[2], off, 64);
        rs[3] += __shfl_xor(rs[3], off, 64);
      }
      if (ln == 0){
        #pragma unroll
        for (int r=0; r<4; ++r) atomicAdd(&rowsum[rbase+r], rs[r]);
      }
    }
  }
}

// ---------------------------------------------------------------------------
// fp32 -> bf16 converter (for lstm_r)
// ---------------------------------------------------------------------------
__global__ __launch_bounds__(256)
void cvt_bf16(const float* __restrict__ src, u16* __restrict__ dst){
  int i = (blockIdx.x*256 + threadIdx.x) * 4;
  f4v v = *(const f4v*)(src + i);
  uint2 p;
  p.x = (u32)f2bf(v.x) | ((u32)f2bf(v.y)<<16);
  p.y = (u32)f2bf(v.z) | ((u32)f2bf(v.w)<<16);
  *(uint2*)(dst + i) = p;
}

// ---------------------------------------------------------------------------
// One LSTM step.  grid 64 = (b, half); block 1024.
// z[col] = xk[b,t,col] + sum_k h[k]*Wr[k,col] + bias[col]; gates -> h,c
// ---------------------------------------------------------------------------
__global__ __launch_bounds__(1024)
void lstm_step(const float* __restrict__ xk, const u16* __restrict__ wr_bf,
               const float* __restrict__ lstm_b,
               const float* __restrict__ h_in, float* __restrict__ h_out,
               float* __restrict__ c_cur, float* __restrict__ hidden,
               float* __restrict__ out_h, float* __restrict__ out_c, int t)
{
  const int b = blockIdx.x >> 1;
  const int half = blockIdx.x & 1;
  __shared__ float hs[NH];
  __shared__ float zs[1024];
  const int tid = threadIdx.x;
  if (tid < NH) hs[tid] = h_in[b*NH + tid];
  __syncthreads();
  const int jl = tid & 255;
  const int g  = tid >> 8;
  const int col = g*NH + half*256 + jl;
  float acc = 0.f;
  const u16* w = wr_bf + col;
  #pragma unroll 8
  for (int k=0; k<NH; ++k) acc += hs[k] * bf2f(w[(size_t)k*2048]);
  acc += xk[(size_t)(b*NT+t)*2048 + col] + lstm_b[col];
  zs[g*256 + jl] = acc;
  __syncthreads();
  if (tid < 256){
    int j = half*256 + tid;
    float zi = zs[tid], zf = zs[256+tid], zg = zs[512+tid], zo = zs[768+tid];
    float c = sigm(zf)*c_cur[b*NH+j] + sigm(zi)*tanhf(zg);
    float h = sigm(zo)*tanhf(c);
    c_cur[b*NH+j] = c;
    h_out[b*NH+j] = h;
    hidden[(size_t)(b*NT+t)*NH + j] = h;
    if (t == NT-1){ out_h[b*NH+j] = h; out_c[b*NH+j] = c; }
  }
}

// ---------------------------------------------------------------------------
// Attention: scores = q . enc, masked softmax over s, context; writes
// concat[r][0:512]=context, concat[r][512:1024]=hidden.  grid 32 (b), 1024 thr.
// ---------------------------------------------------------------------------
__global__ __launch_bounds__(1024)
void attn_ctx(const float* __restrict__ q, const float* __restrict__ enc,
              const int* __restrict__ enc_len, const float* __restrict__ hidden,
              float* __restrict__ concat)
{
  const int b = blockIdx.x;
  __shared__ float qs[NT][NENC];
  __shared__ float at[NT][NS];
  __shared__ float cred[NT][NENC];
  const int tid = threadIdx.x;
  for (int i=tid; i<NT*NENC; i+=1024) ((float*)qs)[i] = q[(size_t)b*NT*NENC + i];
  __syncthreads();
  const int len = enc_len[b];
  { // scores: thread = (s, t-pair)
    int s = tid & 255, tg = (tid >> 8) * 2;
    const float* er = enc + ((size_t)(b*NS+s))*NENC;
    float s0 = 0.f, s1 = 0.f;
    for (int e=0; e<NENC; e+=4){
      f4v v = *(const f4v*)(er+e);
      s0 += v.x*qs[tg][e]   + v.y*qs[tg][e+1]   + v.z*qs[tg][e+2]   + v.w*qs[tg][e+3];
      s1 += v.x*qs[tg+1][e] + v.y*qs[tg+1][e+1] + v.z*qs[tg+1][e+2] + v.w*qs[tg+1][e+3];
    }
    bool m = s < len;
    at[tg][s]   = m ? s0 : -3.0e38f;
    at[tg+1][s] = m ? s1 : -3.0e38f;
  }
  __syncthreads();
  { // softmax: wave w handles t=w
    int wave = tid >> 6, lane = tid & 63;
    if (wave < NT){
      float v[4]; float mx = -3.0e38f;
      #pragma unroll
      for (int i=0;i<4;++i){ v[i] = at[wave][lane+64*i]; mx = fmaxf(mx, v[i]); }
      #pragma unroll
      for (int off=1; off<64; off<<=1) mx = fmaxf(mx, __shfl_xor(mx, off, 64));
      float sum = 0.f;
      #pragma unroll
      for (int i=0;i<4;++i){ v[i] = __expf(v[i]-mx); sum += v[i]; }
      #pragma unroll
      for (int off=1; off<64; off<<=1) sum += __shfl_xor(sum, off, 64);
      float inv = 1.f/sum;
      #pragma unroll
      for (int i=0;i<4;++i) at[wave][lane+64*i] = v[i]*inv;
    }
  }
  __syncthreads();
  { // context: thread = (e, s-half)
    int e = tid & 511, sh = tid >> 9;
    float cx[NT];
    #pragma unroll
    for (int t=0;t<NT;++t) cx[t] = 0.f;
    for (int si=0; si<128; ++si){
      int s = sh*128 + si;
      float v = enc[((size_t)(b*NS+s))*NENC + e];
      #pragma unroll
      for (int t=0;t<NT;++t) cx[t] += at[t][s]*v;
    }
    if (sh == 1){
      #pragma unroll
      for (int t=0;t<NT;++t) cred[t][e] = cx[t];
    }
    __syncthreads();
    if (sh == 0){
      #pragma unroll
      for (int t=0;t<NT;++t)
        concat[(size_t)(b*NT+t)*1024 + e] = cx[t] + cred[t][e];
    } else {
      #pragma unroll
      for (int t=0;t<NT;++t)
        concat[(size_t)(b*NT+t)*1024 + 512 + e] = hidden[(size_t)(b*NT+t)*NH + e];
    }
  }
}

// ---------------------------------------------------------------------------
// OOV region fill: total[r][50000:51000] = 1e-10
// ---------------------------------------------------------------------------
__global__ __launch_bounds__(256)
void oov_fill(float* __restrict__ outp){
  float* p = outp + (size_t)blockIdx.x*NVT + NVOC;
  for (int i=threadIdx.x; i<1000; i+=256) p[i] = 1e-10f;
}

// ---------------------------------------------------------------------------
// cs = exp(attn_out @ copy_k^T) with mask; scatter-add into extended vocab
// + rowsum atomics.  MFMA 16x16x32, M=8 padded to 16. grid 128 = (b, sblk).
// ---------------------------------------------------------------------------
__global__ __launch_bounds__(256)
void cs_scatter(const u16* __restrict__ attn_bf, const u16* __restrict__ copy_k,
                const int* __restrict__ enc_x, const int* __restrict__ enc_len,
                float* __restrict__ outp, float* __restrict__ rowsum)
{
  const int b  = blockIdx.x >> 2;
  const int sb = blockIdx.x & 3;
  __shared__ u16 Al[16*520];
  const int tid = threadIdx.x;
  for (int i=tid; i<16*64; i+=256){      // 1024 chunks of 8 shorts
    int row = i >> 6, ck = i & 63;
    uint2 v0 = {0u,0u}, v1 = {0u,0u};
    if (row < NT){
      const u16* s = attn_bf + ((size_t)(b*NT+row))*NH + ck*8;
      v0 = *(const uint2*)s; v1 = *(const uint2*)(s+4);
    }
    u16* d = &Al[row*520 + ck*8];
    *(uint2*)d = v0; *(uint2*)(d+4) = v1;
  }
  __syncthreads();
  const int wave = tid >> 6, lane = tid & 63;
  const int q = lane >> 4, ln = lane & 15;
  const int s0 = sb*64 + wave*16;
  f4v acc = 0.f;
  const u16* Bg = copy_k + ((size_t)(b*NS + s0 + ln))*NH;
  for (int kb=0; kb<16; ++kb){
    s8v a = ld_frag(&Al[ln*520 + kb*32 + q*8]);
    s8v bb = ld_frag(Bg + kb*32 + q*8);
    acc = mfma16(a, bb, acc);
  }
  const int s = s0 + ln;
  const int len = enc_len[b];
  const int vidx = enc_x[b*NS + s];
  const bool valid = (s < len);
  float rs[4];
  #pragma unroll
  for (int r=0; r<4; ++r){
    int t = q*4 + r;
    float e = (valid && t < NT) ? __expf(acc[r]) : 0.f;
    rs[r] = e;
    if (e != 0.f) atomicAdd(&outp[(size_t)(b*NT+t)*NVT + vidx], e);
  }
  #pragma unroll
  for (int off=1; off<16; off<<=1){
    rs[0] += __shfl_xor(rs[0], off, 64);
    rs[1] += __shfl_xor(rs[1], off, 64);
    rs[2] += __shfl_xor(rs[2], off, 64);
    rs[3] += __shfl_xor(rs[3], off, 64);
  }
  if (ln == 0){
    #pragma unroll
    for (int r=0; r<4; ++r){
      int t = q*4 + r;
      if (t < NT) atomicAdd(&rowsum[b*NT+t], rs[r]);
    }
  }
}

// ---------------------------------------------------------------------------
// rowsum -> log(rowsum + 1000*1e-10) in place (256 rows)
// ---------------------------------------------------------------------------
__global__ void log_rowsum(float* rowsum){
  int i = threadIdx.x;
  rowsum[i] = __logf(rowsum[i] + 1e-7f);
}

// ---------------------------------------------------------------------------
// out = log(total) - logsum[row]   (13,056,000 floats, float4 path)
// ---------------------------------------------------------------------------
__global__ __launch_bounds__(256)
void norm_log(float* __restrict__ outp, const float* __restrict__ logsum){
  const int stride = gridDim.x * 256;
  for (int i4 = blockIdx.x*256 + threadIdx.x; i4 < 3264000; i4 += stride){
    int r = i4 / 12750;                    // 51000/4 float4 per row
    float ls = logsum[r];
    f4v v = *(const f4v*)(outp + (size_t)i4*4);
    v.x = __logf(v.x) - ls;
    v.y = __logf(v.y) - ls;
    v.z = __logf(v.z) - ls;
    v.w = __logf(v.w) - ls;
    *(f4v*)(outp + (size_t)i4*4) = v;
  }
}

// ---------------------------------------------------------------------------
extern "C" void kernel_launch(void* const* d_in, const int* in_sizes, int n_in,
                              void* d_out, int out_size, void* d_ws, size_t ws_size,
                              hipStream_t stream)
{
  (void)in_sizes; (void)n_in; (void)out_size; (void)ws_size;
  const int*   dec_x      = (const int*)  d_in[0];
  const int*   enc_x      = (const int*)  d_in[1];
  const int*   enc_len    = (const int*)  d_in[2];
  const float* enc_output = (const float*)d_in[3];
  const float* enc_h      = (const float*)d_in[4];
  const float* enc_c      = (const float*)d_in[5];
  const float* embedding  = (const float*)d_in[8];
  const float* lstm_k     = (const float*)d_in[9];
  const float* lstm_r     = (const float*)d_in[10];
  const float* lstm_b     = (const float*)d_in[11];
  const float* attn_w     = (const float*)d_in[12];
  const float* out_w      = (const float*)d_in[13];
  const float* out_b      = (const float*)d_in[14];
  const float* gen_w      = (const float*)d_in[15];
  const float* copy_w     = (const float*)d_in[16];
  const float* copy_b     = (const float*)d_in[17];

  float* outp  = (float*)d_out;
  float* out_h = outp + (size_t)NB*NT*NVT;       // 13,056,000
  float* out_c = out_h + NB*NH;

  char* ws = (char*)d_ws;
  u16*   wr_bf   = (u16*)ws;    ws += (size_t)NH*2048*2;      // 2 MB
  float* xk      = (float*)ws;  ws += (size_t)NB*NT*2048*4;   // 2 MB
  float* hbuf0   = (float*)ws;  ws += NB*NH*4;
  float* hbuf1   = (float*)ws;  ws += NB*NH*4;
  float* c_cur   = (float*)ws;  ws += NB*NH*4;
  float* hidden  = (float*)ws;  ws += (size_t)NB*NT*NH*4;     // 512 KB
  float* qbuf    = (float*)ws;  ws += (size_t)NB*NT*NENC*4;   // 512 KB
  float* concat  = (float*)ws;  ws += (size_t)NB*NT*1024*4;   // 1 MB
  u16*   attn_bf = (u16*)ws;    ws += (size_t)NB*NT*NH*2;     // 256 KB
  u16*   copy_k  = (u16*)ws;    ws += (size_t)NB*NS*NH*2;     // 8 MB
  float* rowsum  = (float*)ws;  ws += NB*NT*4;

  hipMemsetAsync(rowsum, 0, NB*NT*4, stream);
  cvt_bf16<<<1024,256,0,stream>>>(lstm_r, wr_bf);             // 512*2048 / 1024

  // xk = embedding[dec_x] @ lstm_k   (M=256, K=256, N=2048)
  gemm_mfma<64,64,0,false,true><<<dim3(4,32),256,0,stream>>>(
      embedding, lstm_k, xk, dec_x, nullptr, nullptr, 256, NEMB, 2048, 2048, 2048);

  hipMemcpyAsync(hbuf0, enc_h, NB*NH*4, hipMemcpyDeviceToDevice, stream);
  hipMemcpyAsync(c_cur, enc_c, NB*NH*4, hipMemcpyDeviceToDevice, stream);

  float* hb[2] = {hbuf0, hbuf1};
  for (int t=0; t<NT; ++t)
    lstm_step<<<64,1024,0,stream>>>(xk, wr_bf, lstm_b, hb[t&1], hb[(t+1)&1],
                                    c_cur, hidden, out_h, out_c, t);

  // q = hidden @ attn_w  (M=256, K=512, N=512)
  gemm_mfma<64,64,0,false,false><<<dim3(4,8),256,0,stream>>>(
      hidden, attn_w, qbuf, nullptr, nullptr, nullptr, NH, NH, NENC, NENC, NENC);

  attn_ctx<<<32,1024,0,stream>>>(qbuf, enc_output, enc_len, hidden, concat);

  // attn_out = tanh(concat @ out_w + out_b) -> bf16  (M=256, K=1024, N=512)
  gemm_mfma<64,64,1,false,false><<<dim3(4,8),256,0,stream>>>(
      concat, out_w, (float*)attn_bf, nullptr, out_b, nullptr, 1024, 1024, NH, NH, NH);

  // copy_k = tanh(enc_output @ copy_w + copy_b) -> bf16 (M=8192, K=512, N=512)
  gemm_mfma<128,128,1,false,false><<<dim3(64,4),256,0,stream>>>(
      enc_output, copy_w, (float*)copy_k, nullptr, copy_b, nullptr, NENC, NENC, NH, NH, NH);

  // gen = exp(attn_out @ gen_w) -> out + row sums (M=256, K=512, N=50000)
  gemm_mfma<128,128,2,true,false><<<dim3(2,391),256,0,stream>>>(
      attn_bf, gen_w, outp, nullptr, nullptr, rowsum, NH, NH, NVOC, NVT, NVOC);

  oov_fill<<<NB*NT,256,0,stream>>>(outp);
  cs_scatter<<<128,256,0,stream>>>(attn_bf, copy_k, enc_x, enc_len, outp, rowsum);
  log_rowsum<<<1,NB*NT,0,stream>>>(rowsum);
  norm_log<<<1594,256,0,stream>>>(outp, rowsum);
}